// Round 5
// baseline (229.483 us; speedup 1.0000x reference)
//
#include <hip/hip_runtime.h>
#include <hip/hip_bf16.h>

#define NB   32
#define H    1024
#define W    1024
#define BAND 16              // output rows per block
#define NBANDS (H / BAND)    // 64 bands per image
#define ROWS (BAND + 6)      // 22 input rows streamed per block
#define TOPK 200
#define NMS_THRESH 0.1f
#define HI_THRESH  0.999f    // fast-path split; exact fallback preserved
#define CAPH 64              // hi keys per band bucket (E~16, Poisson-safe)
#define LBL  512             // LDS lo buffer per block (E~335, ~9.7 sigma)

typedef unsigned long long ull;

__device__ __forceinline__ float4 fmax4(float4 a, float4 b) {
    return make_float4(fmaxf(a.x, b.x), fmaxf(a.y, b.y),
                       fmaxf(a.z, b.z), fmaxf(a.w, b.w));
}

// ---------------- Phase 1: streaming 7x7 NMS ----------------
// Thread t owns cols [4t,4t+4). Block = 1024 cols x 16 output rows.
// Vertical max: plain ring of 7 horizontal-max rows + 6 fmax4 per output
// row (cheap VALU, minimal registers -> no spills, high occupancy).
// Peaks: per-thread predicate, rare branch, LDS atomic slot, one coalesced
// flush per block to its private bucket. Zero global atomics, no memset.
__global__ __launch_bounds__(256) void peak_kernel(
    const float* __restrict__ in,
    ull* __restrict__ cand_hi,   // [NB*NBANDS][CAPH]
    ull* __restrict__ cand_lo,   // [NB*NBANDS][capl]
    int* __restrict__ cntl,      // [NB*NBANDS]
    int* __restrict__ cnth,      // [NB*NBANDS], -1 => hi overflow, force lo path
    int capl)
{
    __shared__ ull lb_lo[LBL];   // 4 KB
    __shared__ ull lb_hi[CAPH];  // 512 B
    __shared__ int lc_lo, lc_hi;

    const int img  = blockIdx.y;
    const int band = blockIdx.x;
    const int R0   = band * BAND;
    const char* base = (const char*)(in + ((size_t)img << 20));
    const int t = threadIdx.x;

    if (t == 0) { lc_lo = 0; lc_hi = 0; }
    __syncthreads();

    const int  cb  = t << 4;                      // own quad byte offset in row
    const int  cbL = (t == 0)   ? cb : cb - 16;
    const int  cbR = (t == 255) ? cb : cb + 16;
    const bool eL  = (t == 0), eR = (t == 255);

    float4 h[7];   // ring of horizontal 7-max rows
    float4 c[4];   // ring of own center quads (read at lag 3)

    #pragma unroll
    for (int r = 0; r < ROWS; r++) {
        const int ri = R0 - 3 + r;
        float4 ho, own;
        if (ri < 0 || ri >= H) {                  // wave-uniform edge rows
            ho  = make_float4(-1.f, -1.f, -1.f, -1.f);
            own = ho;
        } else {
            const char* rp = base + ((size_t)ri << 12);
            own        = *(const float4*)(rp + cb);
            float4 lq  = *(const float4*)(rp + cbL);
            float4 rq  = *(const float4*)(rp + cbR);
            if (eL) { lq.y = -1.f; lq.z = -1.f; lq.w = -1.f; }
            if (eR) { rq.x = -1.f; rq.y = -1.f; rq.z = -1.f; }
            // horizontal 7-max via prefix/suffix over v0..v9 =
            // lq.y lq.z lq.w own.x own.y own.z own.w rq.x rq.y rq.z
            float S3 = own.x;
            float S2 = fmaxf(lq.w, S3);
            float S1 = fmaxf(lq.z, S2);
            float S0 = fmaxf(lq.y, S1);
            float P4 = own.y;
            float P5 = fmaxf(P4, own.z);
            float P6 = fmaxf(P5, own.w);
            float P7 = fmaxf(P6, rq.x);
            float P8 = fmaxf(P7, rq.y);
            float P9 = fmaxf(P8, rq.z);
            ho = make_float4(fmaxf(S0, P6), fmaxf(S1, P7),
                             fmaxf(S2, P8), fmaxf(S3, P9));
        }
        h[r % 7] = ho;
        c[r & 3] = own;

        if (r >= 6) {
            // window max over the 7 resident h rows
            float4 wm = fmax4(fmax4(fmax4(h[0], h[1]), fmax4(h[2], h[3])),
                              fmax4(fmax4(h[4], h[5]), h[6]));
            float4 ctr = c[(r + 1) & 3];          // centers of row ro = ri-3
            const int ro = R0 + (r - 6);
            bool p0 = (ctr.x > NMS_THRESH) && (ctr.x == wm.x);
            bool p1 = (ctr.y > NMS_THRESH) && (ctr.y == wm.y);
            bool p2 = (ctr.z > NMS_THRESH) && (ctr.z == wm.z);
            bool p3 = (ctr.w > NMS_THRESH) && (ctr.w == wm.w);
            int cnt = (int)p0 + (int)p1 + (int)p2 + (int)p3;
            if (cnt) {                             // ~8% of thread-rows
                int s = atomicAdd(&lc_lo, cnt);
                unsigned ib = ((unsigned)ro << 10) | ((unsigned)t << 2);
                float cv[4] = {ctr.x, ctr.y, ctr.z, ctr.w};
                bool  pp[4] = {p0, p1, p2, p3};
                #pragma unroll
                for (int j = 0; j < 4; j++) {
                    if (pp[j]) {
                        ull key = ((ull)__float_as_uint(cv[j]) << 32) |
                                  (ull)(0xFFFFFFFFu - (ib + j));
                        if (s < LBL) lb_lo[s] = key;
                        s++;
                        if (cv[j] > HI_THRESH) {   // ~1/1000 pixels
                            int q = atomicAdd(&lc_hi, 1);
                            if (q < CAPH) lb_hi[q] = key;
                        }
                    }
                }
            }
        }
    }

    // ---- flush: coalesced stores to this block's bucket ----
    __syncthreads();
    const int bkt = img * NBANDS + band;
    const int nl_raw = lc_lo, nh_raw = lc_hi;
    const int nl = min(nl_raw, min(LBL, capl));
    const int nh = min(nh_raw, CAPH);
    ull* glo = cand_lo + (size_t)bkt * capl;
    for (int i = t; i < nl; i += 256) glo[i] = lb_lo[i];
    ull* ghi = cand_hi + (size_t)bkt * CAPH;
    if (t < nh) ghi[t] = lb_hi[t];
    if (t == 0) {
        cntl[bkt] = nl;
        // -1 flags hi overflow (keys dropped from hi but present in lo);
        // topk then falls back to the exact lo path.
        cnth[bkt] = (nh_raw > CAPH) ? -1 : nh_raw;
    }
}

// ---------------- Phase 2: per-image exact top-200 ----------------
// hi buckets (> 0.999) total ~1000 keys; if nh_total >= 200 (and no bucket
// overflowed) the top-200 is provably inside hi: every non-hi value
// <= 0.999 < any hi value. Staged to LDS, radix-select over value bits,
// exact tie-break via full-key bitonic sort. Fallback: bucketed global
// scan over lo lists (= ALL peaks).
__global__ __launch_bounds__(256) void topk_kernel(
    const ull* __restrict__ cand_hi,
    const ull* __restrict__ cand_lo,
    const int* __restrict__ cntl,
    const int* __restrict__ cnth,
    float* __restrict__ out,
    int capl)
{
    const int img = blockIdx.x;
    const int t = threadIdx.x;
    const int wv = t >> 6;
    __shared__ ull stage[NBANDS * CAPH];   // 32 KB: all hi keys fit
    __shared__ unsigned hist[4][256];      // wave-private histograms
    __shared__ unsigned sfx[256];
    __shared__ ull sel[256];
    __shared__ int s_ch[NBANDS], s_cl[NBANDS], s_oh[NBANDS + 1];
    __shared__ int s_ok;
    __shared__ int scnt;
    __shared__ unsigned s_pref;
    __shared__ int s_k;

    if (t < NBANDS) {
        int raw = cnth[img * NBANDS + t];
        s_ch[t] = max(raw, 0);
        s_cl[t] = cntl[img * NBANDS + t];
        if (raw < 0) atomicAnd(&s_ok, 0);
    }
    if (t == 0) s_ok = 1;
    __syncthreads();
    if (t < NBANDS) {
        if (cnth[img * NBANDS + t] < 0) s_ok = 0;   // after init, pre-scan
    }
    __syncthreads();
    if (t == 0) {
        int a = 0;
        for (int b = 0; b < NBANDS; b++) { s_oh[b] = a; a += s_ch[b]; }
        s_oh[NBANDS] = a;
    }
    __syncthreads();
    const int nh = s_oh[NBANDS];
    const bool use_hi = (nh >= TOPK) && (s_ok != 0);

    if (use_hi) {
        int b = t >> 2, i0 = t & 3;                 // 4 threads per band
        int nb = s_ch[b], ob = s_oh[b];
        const ull* p = cand_hi + (size_t)(img * NBANDS + b) * CAPH;
        for (int i = i0; i < nb; i += 4) stage[ob + i] = p[i];
    }
    __syncthreads();

    int n_tot = nh;
    if (!use_hi) {
        n_tot = 0;
        for (int b = 0; b < NBANDS; b++) n_tot += s_cl[b];
    }

    unsigned T = 0;   // value-bits threshold (200th-largest value)
    if (n_tot > TOPK) {
        unsigned prefix = 0, maskhi = 0;
        int kk = TOPK;
        for (int byte = 3; byte >= 0; byte--) {
            #pragma unroll
            for (int w = 0; w < 4; w++) hist[w][t] = 0;
            __syncthreads();
            const int shift = byte * 8;
            if (use_hi) {
                for (int i = t; i < nh; i += 256) {
                    unsigned vb = (unsigned)(stage[i] >> 32);
                    if ((vb & maskhi) == prefix)
                        atomicAdd(&hist[wv][(vb >> shift) & 0xFFu], 1u);
                }
            } else {
                for (int b = 0; b < NBANDS; b++) {
                    int nb = s_cl[b];
                    const ull* p = cand_lo + (size_t)(img * NBANDS + b) * capl;
                    for (int i = t; i < nb; i += 256) {
                        unsigned vb = (unsigned)(p[i] >> 32);
                        if ((vb & maskhi) == prefix)
                            atomicAdd(&hist[wv][(vb >> shift) & 0xFFu], 1u);
                    }
                }
            }
            __syncthreads();
            sfx[t] = hist[0][t] + hist[1][t] + hist[2][t] + hist[3][t];
            __syncthreads();
            for (int off = 1; off < 256; off <<= 1) {
                unsigned u = (t + off < 256) ? sfx[t + off] : 0u;
                __syncthreads();
                sfx[t] += u;
                __syncthreads();
            }
            unsigned nxt = (t == 255) ? 0u : sfx[t + 1];
            if (sfx[t] >= (unsigned)kk && nxt < (unsigned)kk) {
                s_pref = prefix | ((unsigned)t << shift);
                s_k = kk - (int)nxt;
            }
            __syncthreads();
            prefix = s_pref;
            kk = s_k;
            maskhi |= (0xFFu << shift);
            __syncthreads();
        }
        T = prefix;
    }

    if (t == 0) scnt = 0;
    __syncthreads();
    if (use_hi) {
        for (int i = t; i < nh; i += 256) {
            ull k = stage[i];
            if ((unsigned)(k >> 32) >= T) {
                int s = atomicAdd(&scnt, 1);
                if (s < 256) sel[s] = k;
            }
        }
    } else {
        for (int b = 0; b < NBANDS; b++) {
            int nb = s_cl[b];
            const ull* p = cand_lo + (size_t)(img * NBANDS + b) * capl;
            for (int i = t; i < nb; i += 256) {
                ull k = p[i];
                if ((unsigned)(k >> 32) >= T) {
                    int s = atomicAdd(&scnt, 1);
                    if (s < 256) sel[s] = k;
                }
            }
        }
    }
    __syncthreads();
    const int m = min(scnt, 256);
    if (t >= m) sel[t] = 0ull;
    __syncthreads();

    // bitonic sort 256 keys, descending
    for (int k2 = 2; k2 <= 256; k2 <<= 1) {
        for (int j = k2 >> 1; j > 0; j >>= 1) {
            int ixj = t ^ j;
            if (ixj > t) {
                ull a = sel[t], b = sel[ixj];
                bool descBlock = ((t & k2) == 0);
                bool sw = descBlock ? (a < b) : (a > b);
                if (sw) { sel[t] = b; sel[ixj] = a; }
            }
            __syncthreads();
        }
    }

    // write: coords [NB,TOPK,2] then probs [NB,TOPK], all fp32
    const int meff = min(m, TOPK);
    if (t < TOPK) {
        float prob = 0.0f;
        unsigned row = 0, col = 0;
        if (t < meff) {
            ull key = sel[t];
            prob = __uint_as_float((unsigned)(key >> 32));
            unsigned idx = 0xFFFFFFFFu - (unsigned)(key & 0xFFFFFFFFull);
            row = idx >> 10;
            col = idx & (W - 1);
        }
        size_t cbase = (size_t)img * TOPK * 2 + (size_t)t * 2;
        out[cbase + 0] = (float)row;
        out[cbase + 1] = (float)col;
        out[(size_t)NB * TOPK * 2 + (size_t)img * TOPK + t] = prob;
    }
}

extern "C" void kernel_launch(void* const* d_in, const int* in_sizes, int n_in,
                              void* d_out, int out_size, void* d_ws, size_t ws_size,
                              hipStream_t stream) {
    const float* center_map = (const float*)d_in[0];
    float* out = (float*)d_out;

    // workspace layout (all counts plain-stored by peak_kernel; no memset):
    //   [0, 8K)      : cntl[2048]
    //   [8K, 16K)    : cnth[2048]
    //   [16K, +1M)   : cand_hi[2048][CAPH]
    //   rest         : cand_lo[2048][capl]
    const int nbkt = NB * NBANDS;   // 2048
    int* cntl = (int*)d_ws;
    int* cnth = (int*)((char*)d_ws + 8192);
    ull* cand_hi = (ull*)((char*)d_ws + 16384);
    size_t hi_bytes = (size_t)nbkt * CAPH * sizeof(ull);   // 1 MB
    ull* cand_lo = (ull*)((char*)d_ws + 16384 + hi_bytes);
    size_t avail = (ws_size > 16384 + hi_bytes) ? (ws_size - 16384 - hi_bytes) : 0;
    int capl = (int)(avail / (nbkt * sizeof(ull)));
    if (capl > LBL) capl = LBL;
    if (capl < 1) capl = 1;

    dim3 gridA(NBANDS, NB);   // 64 x 32 = 2048 blocks
    peak_kernel<<<gridA, 256, 0, stream>>>(center_map, cand_hi, cand_lo,
                                           cntl, cnth, capl);

    topk_kernel<<<NB, 256, 0, stream>>>(cand_hi, cand_lo, cntl, cnth, out, capl);
}

// Round 6
// 219.732 us; speedup vs baseline: 1.0444x; 1.0444x over previous
//
#include <hip/hip_runtime.h>
#include <hip/hip_bf16.h>

#define NB   32
#define H    1024
#define W    1024
#define BAND 8               // output rows per block
#define NBANDS (H / BAND)    // 128 bands per image
#define ROWS (BAND + 6)      // 14 input rows per block
#define TOPK 200
#define NMS_THRESH 0.1f
#define HI_THRESH  0.999f    // fast-path split; exact fallback preserved
#define CAPH 32              // hi keys per band bucket (E~8)
#define LBL  384             // LDS lo buffer per block (E~167, ~+16 sigma)

typedef unsigned long long ull;

__device__ __forceinline__ float4 fmax4(float4 a, float4 b) {
    return make_float4(fmaxf(a.x, b.x), fmaxf(a.y, b.y),
                       fmaxf(a.z, b.z), fmaxf(a.w, b.w));
}

// ---------------- Phase 1: 7x7 NMS, burst-load + register window ----------
// Thread t owns cols [4t,4t+4). Block = 1024 cols x 8 output rows.
// Phase A: load ALL 14 rows (42 independent float4 loads, no atomics or
// side effects in the loop -> compiler pipelines the full burst; serial
// latency chain of the old streaming version is gone).
// Phase B: static-index 7-row window max + emit into LDS buckets.
// __launch_bounds__(256,3): cap ~170 VGPR (h[14]+c[8]=88 floats live),
// no spill, >=3 waves/SIMD.
__global__ __launch_bounds__(256, 3) void peak_kernel(
    const float* __restrict__ in,
    ull* __restrict__ cand_hi,   // [NB*NBANDS][CAPH]
    ull* __restrict__ cand_lo,   // [NB*NBANDS][capl]
    int* __restrict__ cntl,      // [NB*NBANDS]
    int* __restrict__ cnth,      // [NB*NBANDS], -1 => hi overflow -> lo path
    int capl)
{
    __shared__ ull lb_lo[LBL];   // 3 KB
    __shared__ ull lb_hi[CAPH];  // 256 B
    __shared__ int lc_lo, lc_hi;

    const int img  = blockIdx.y;
    const int band = blockIdx.x;
    const int R0   = band * BAND;
    const char* base = (const char*)(in + ((size_t)img << 20));
    const int t = threadIdx.x;

    if (t == 0) { lc_lo = 0; lc_hi = 0; }

    const int  cb  = t << 4;                      // own quad byte offset
    const int  cbL = (t == 0)   ? cb : cb - 16;
    const int  cbR = (t == 255) ? cb : cb + 16;
    const bool eL  = (t == 0), eR = (t == 255);

    float4 h[ROWS];   // horizontal 7-max of every input row
    float4 c[BAND];   // own centers for output rows (input rows 3..10)

    // ---- Phase A: burst load + horizontal max, zero side effects ----
    #pragma unroll
    for (int r = 0; r < ROWS; r++) {
        const int ri  = R0 - 3 + r;
        const int riC = min(max(ri, 0), H - 1);
        const bool valid = (ri == riC);
        const char* rp = base + ((size_t)riC << 12);
        float4 own = *(const float4*)(rp + cb);
        float4 lq  = *(const float4*)(rp + cbL);
        float4 rq  = *(const float4*)(rp + cbR);
        if (eL) { lq.y = -1.f; lq.z = -1.f; lq.w = -1.f; }
        if (eR) { rq.x = -1.f; rq.y = -1.f; rq.z = -1.f; }
        // horizontal 7-max via prefix/suffix over v0..v9 =
        // lq.y lq.z lq.w own.x own.y own.z own.w rq.x rq.y rq.z
        float S3 = own.x;
        float S2 = fmaxf(lq.w, S3);
        float S1 = fmaxf(lq.z, S2);
        float S0 = fmaxf(lq.y, S1);
        float P4 = own.y;
        float P5 = fmaxf(P4, own.z);
        float P6 = fmaxf(P5, own.w);
        float P7 = fmaxf(P6, rq.x);
        float P8 = fmaxf(P7, rq.y);
        float P9 = fmaxf(P8, rq.z);
        float4 ho = make_float4(fmaxf(S0, P6), fmaxf(S1, P7),
                                fmaxf(S2, P8), fmaxf(S3, P9));
        const float4 neg1 = make_float4(-1.f, -1.f, -1.f, -1.f);
        h[r] = valid ? ho : neg1;
        if (r >= 3 && r < 3 + BAND) c[r - 3] = valid ? own : neg1;
    }
    __syncthreads();   // lc_lo/lc_hi init visible before emits

    // ---- Phase B: vertical window + peak emit (static indices) ----
    #pragma unroll
    for (int ro = 0; ro < BAND; ro++) {
        float4 wm = fmax4(fmax4(fmax4(h[ro], h[ro + 1]),
                                fmax4(h[ro + 2], h[ro + 3])),
                          fmax4(fmax4(h[ro + 4], h[ro + 5]), h[ro + 6]));
        float4 ctr = c[ro];
        const int rg = R0 + ro;
        bool p0 = (ctr.x > NMS_THRESH) && (ctr.x == wm.x);
        bool p1 = (ctr.y > NMS_THRESH) && (ctr.y == wm.y);
        bool p2 = (ctr.z > NMS_THRESH) && (ctr.z == wm.z);
        bool p3 = (ctr.w > NMS_THRESH) && (ctr.w == wm.w);
        int cnt = (int)p0 + (int)p1 + (int)p2 + (int)p3;
        if (cnt) {                                // ~8% of thread-rows
            int s = atomicAdd(&lc_lo, cnt);
            unsigned ib = ((unsigned)rg << 10) | ((unsigned)t << 2);
            float cv[4] = {ctr.x, ctr.y, ctr.z, ctr.w};
            bool  pp[4] = {p0, p1, p2, p3};
            #pragma unroll
            for (int j = 0; j < 4; j++) {
                if (pp[j]) {
                    ull key = ((ull)__float_as_uint(cv[j]) << 32) |
                              (ull)(0xFFFFFFFFu - (ib + j));
                    if (s < LBL) lb_lo[s] = key;
                    s++;
                    if (cv[j] > HI_THRESH) {      // ~1/20 of peaks
                        int q = atomicAdd(&lc_hi, 1);
                        if (q < CAPH) lb_hi[q] = key;
                    }
                }
            }
        }
    }

    // ---- flush: coalesced stores to this block's private bucket ----
    __syncthreads();
    const int bkt = img * NBANDS + band;
    const int nl_raw = lc_lo, nh_raw = lc_hi;
    const int nl = min(nl_raw, min(LBL, capl));
    const int nh = min(nh_raw, CAPH);
    ull* glo = cand_lo + (size_t)bkt * capl;
    for (int i = t; i < nl; i += 256) glo[i] = lb_lo[i];
    ull* ghi = cand_hi + (size_t)bkt * CAPH;
    if (t < nh) ghi[t] = lb_hi[t];
    if (t == 0) {
        cntl[bkt] = nl;
        cnth[bkt] = (nh_raw > CAPH) ? -1 : nh_raw;   // -1: force exact lo path
    }
}

// ---------------- Phase 2: per-image exact top-200 ----------------
// hi buckets (> 0.999) total ~1000 keys; if nh_total >= 200 and no bucket
// overflowed, top-200 is provably inside hi (every non-hi value <= 0.999 <
// any hi value). Staged to LDS, radix-select over value bits, exact
// tie-break via full-key bitonic sort. Fallback: bucketed scan of lo lists
// (= ALL peaks).
__global__ __launch_bounds__(256) void topk_kernel(
    const ull* __restrict__ cand_hi,
    const ull* __restrict__ cand_lo,
    const int* __restrict__ cntl,
    const int* __restrict__ cnth,
    float* __restrict__ out,
    int capl)
{
    const int img = blockIdx.x;
    const int t = threadIdx.x;
    const int wv = t >> 6;
    __shared__ ull stage[NBANDS * CAPH];   // 32 KB: all hi keys fit
    __shared__ unsigned hist[4][256];      // wave-private histograms
    __shared__ unsigned sfx[256];
    __shared__ ull sel[256];
    __shared__ int s_ch[NBANDS], s_cl[NBANDS], s_oh[NBANDS + 1];
    __shared__ int s_ok;
    __shared__ int scnt;
    __shared__ unsigned s_pref;
    __shared__ int s_k;

    if (t == 0) s_ok = 1;
    __syncthreads();
    if (t < NBANDS) {
        int raw = cnth[img * NBANDS + t];
        s_ch[t] = max(raw, 0);
        s_cl[t] = cntl[img * NBANDS + t];
        if (raw < 0) s_ok = 0;       // benign race: all writers store 0
    }
    __syncthreads();
    if (t == 0) {
        int a = 0;
        for (int b = 0; b < NBANDS; b++) { s_oh[b] = a; a += s_ch[b]; }
        s_oh[NBANDS] = a;
    }
    __syncthreads();
    const int nh = s_oh[NBANDS];
    const bool use_hi = (nh >= TOPK) && (s_ok != 0);

    if (use_hi) {
        int b = t >> 1, i0 = t & 1;              // 2 threads per band
        int nb = s_ch[b], ob = s_oh[b];
        const ull* p = cand_hi + (size_t)(img * NBANDS + b) * CAPH;
        for (int i = i0; i < nb; i += 2) stage[ob + i] = p[i];
    }
    __syncthreads();

    int n_tot = nh;
    if (!use_hi) {
        n_tot = 0;
        for (int b = 0; b < NBANDS; b++) n_tot += s_cl[b];
    }

    unsigned T = 0;   // value-bits threshold (200th-largest value)
    if (n_tot > TOPK) {
        unsigned prefix = 0, maskhi = 0;
        int kk = TOPK;
        for (int byte = 3; byte >= 0; byte--) {
            #pragma unroll
            for (int w = 0; w < 4; w++) hist[w][t] = 0;
            __syncthreads();
            const int shift = byte * 8;
            if (use_hi) {
                for (int i = t; i < nh; i += 256) {
                    unsigned vb = (unsigned)(stage[i] >> 32);
                    if ((vb & maskhi) == prefix)
                        atomicAdd(&hist[wv][(vb >> shift) & 0xFFu], 1u);
                }
            } else {
                for (int b = 0; b < NBANDS; b++) {
                    int nb = s_cl[b];
                    const ull* p = cand_lo + (size_t)(img * NBANDS + b) * capl;
                    for (int i = t; i < nb; i += 256) {
                        unsigned vb = (unsigned)(p[i] >> 32);
                        if ((vb & maskhi) == prefix)
                            atomicAdd(&hist[wv][(vb >> shift) & 0xFFu], 1u);
                    }
                }
            }
            __syncthreads();
            sfx[t] = hist[0][t] + hist[1][t] + hist[2][t] + hist[3][t];
            __syncthreads();
            for (int off = 1; off < 256; off <<= 1) {
                unsigned u = (t + off < 256) ? sfx[t + off] : 0u;
                __syncthreads();
                sfx[t] += u;
                __syncthreads();
            }
            unsigned nxt = (t == 255) ? 0u : sfx[t + 1];
            if (sfx[t] >= (unsigned)kk && nxt < (unsigned)kk) {
                s_pref = prefix | ((unsigned)t << shift);
                s_k = kk - (int)nxt;
            }
            __syncthreads();
            prefix = s_pref;
            kk = s_k;
            maskhi |= (0xFFu << shift);
            __syncthreads();
        }
        T = prefix;
    }

    if (t == 0) scnt = 0;
    __syncthreads();
    if (use_hi) {
        for (int i = t; i < nh; i += 256) {
            ull k = stage[i];
            if ((unsigned)(k >> 32) >= T) {
                int s = atomicAdd(&scnt, 1);
                if (s < 256) sel[s] = k;
            }
        }
    } else {
        for (int b = 0; b < NBANDS; b++) {
            int nb = s_cl[b];
            const ull* p = cand_lo + (size_t)(img * NBANDS + b) * capl;
            for (int i = t; i < nb; i += 256) {
                ull k = p[i];
                if ((unsigned)(k >> 32) >= T) {
                    int s = atomicAdd(&scnt, 1);
                    if (s < 256) sel[s] = k;
                }
            }
        }
    }
    __syncthreads();
    const int m = min(scnt, 256);
    if (t >= m) sel[t] = 0ull;
    __syncthreads();

    // bitonic sort 256 keys, descending
    for (int k2 = 2; k2 <= 256; k2 <<= 1) {
        for (int j = k2 >> 1; j > 0; j >>= 1) {
            int ixj = t ^ j;
            if (ixj > t) {
                ull a = sel[t], b = sel[ixj];
                bool descBlock = ((t & k2) == 0);
                bool sw = descBlock ? (a < b) : (a > b);
                if (sw) { sel[t] = b; sel[ixj] = a; }
            }
            __syncthreads();
        }
    }

    // write: coords [NB,TOPK,2] then probs [NB,TOPK], all fp32
    const int meff = min(m, TOPK);
    if (t < TOPK) {
        float prob = 0.0f;
        unsigned row = 0, col = 0;
        if (t < meff) {
            ull key = sel[t];
            prob = __uint_as_float((unsigned)(key >> 32));
            unsigned idx = 0xFFFFFFFFu - (unsigned)(key & 0xFFFFFFFFull);
            row = idx >> 10;
            col = idx & (W - 1);
        }
        size_t cbase = (size_t)img * TOPK * 2 + (size_t)t * 2;
        out[cbase + 0] = (float)row;
        out[cbase + 1] = (float)col;
        out[(size_t)NB * TOPK * 2 + (size_t)img * TOPK + t] = prob;
    }
}

extern "C" void kernel_launch(void* const* d_in, const int* in_sizes, int n_in,
                              void* d_out, int out_size, void* d_ws, size_t ws_size,
                              hipStream_t stream) {
    const float* center_map = (const float*)d_in[0];
    float* out = (float*)d_out;

    // workspace layout (all counts plain-stored by peak_kernel; no memset):
    //   [0, 16K)      : cntl[4096]
    //   [16K, 32K)    : cnth[4096]
    //   [32K, +1M)    : cand_hi[4096][CAPH]
    //   rest          : cand_lo[4096][capl]
    const int nbkt = NB * NBANDS;   // 4096
    int* cntl = (int*)d_ws;
    int* cnth = (int*)((char*)d_ws + 16384);
    ull* cand_hi = (ull*)((char*)d_ws + 32768);
    size_t hi_bytes = (size_t)nbkt * CAPH * sizeof(ull);   // 1 MB
    ull* cand_lo = (ull*)((char*)d_ws + 32768 + hi_bytes);
    size_t avail = (ws_size > 32768 + hi_bytes) ? (ws_size - 32768 - hi_bytes) : 0;
    int capl = (int)(avail / (nbkt * sizeof(ull)));
    if (capl > LBL) capl = LBL;
    if (capl < 1) capl = 1;

    dim3 gridA(NBANDS, NB);   // 128 x 32 = 4096 blocks
    peak_kernel<<<gridA, 256, 0, stream>>>(center_map, cand_hi, cand_lo,
                                           cntl, cnth, capl);

    topk_kernel<<<NB, 256, 0, stream>>>(cand_hi, cand_lo, cntl, cnth, out, capl);
}

// Round 7
// 215.443 us; speedup vs baseline: 1.0652x; 1.0199x over previous
//
#include <hip/hip_runtime.h>
#include <hip/hip_bf16.h>

#define NB   32
#define H    1024
#define W    1024
#define BAND 8               // output rows per block
#define NBANDS (H / BAND)    // 128 bands per image
#define ROWS (BAND + 6)      // 14 input rows per block
#define TOPK 200
#define NMS_THRESH 0.1f
#define HI_THRESH  0.999f    // fast-path split; exact fallback preserved
#define CAPH 32              // hi keys per band bucket (E~8)
#define LBL  384             // LDS lo buffer per block (E~167, ~+16 sigma)

typedef unsigned long long ull;

__device__ __forceinline__ float4 fmax4(float4 a, float4 b) {
    return make_float4(fmaxf(a.x, b.x), fmaxf(a.y, b.y),
                       fmaxf(a.z, b.z), fmaxf(a.w, b.w));
}

// ---------------- Phase 1: 7x7 NMS, forced-burst loads ----------------
// Thread t owns cols [4t,4t+4). Block = 1024 cols x 8 output rows.
// Two 7-row bursts; each burst = pure load loop (21 independent float4
// loads into scalarized arrays, NO consumers) then a compute loop. This
// denies the register-pressure scheduler any reason to sink loads ->
// ~21 outstanding loads/wave (R5 had ~2, VGPR_Count 36 proved it).
// Row/col CLAMPED addressing is exact for max-pool padding: a window
// containing duplicated edge rows/cols has the same max as the -inf-padded
// window (duplicates are elements already inside the window). This deletes
// all edge cndmask fix-ups from the hot loop.
__global__ __launch_bounds__(256, 2) void peak_kernel(
    const float* __restrict__ in,
    ull* __restrict__ cand_hi,   // [NB*NBANDS][CAPH]
    ull* __restrict__ cand_lo,   // [NB*NBANDS][capl]
    int* __restrict__ cntl,      // [NB*NBANDS]
    int* __restrict__ cnth,      // [NB*NBANDS], -1 => hi overflow -> lo path
    int capl)
{
    __shared__ ull lb_lo[LBL];   // 3 KB
    __shared__ ull lb_hi[CAPH];  // 256 B
    __shared__ int lc_lo, lc_hi;

    const int img  = blockIdx.y;
    const int band = blockIdx.x;
    const int R0   = band * BAND;
    const char* base = (const char*)(in + ((size_t)img << 20));
    const int t = threadIdx.x;

    if (t == 0) { lc_lo = 0; lc_hi = 0; }

    const int cb  = t << 4;                       // own quad byte offset
    const int cbL = (t == 0)   ? cb : cb - 16;    // clamped left quad
    const int cbR = (t == 255) ? cb : cb + 16;    // clamped right quad

    float4 h[ROWS];   // horizontal 7-max per input row
    float4 c[BAND];   // own centers for output rows (input rows 3..10)

    #pragma unroll
    for (int half = 0; half < 2; half++) {
        const int rb = half * 7;
        float4 oq[7], lq[7], rq[7];
        // ---- burst load: 21 independent loads, zero consumers ----
        #pragma unroll
        for (int r = 0; r < 7; r++) {
            const int ri = min(max(R0 - 3 + rb + r, 0), H - 1);  // exact clamp
            const char* rp = base + ((size_t)ri << 12);
            oq[r] = *(const float4*)(rp + cb);
            lq[r] = *(const float4*)(rp + cbL);
            rq[r] = *(const float4*)(rp + cbR);
        }
        // ---- consume: horizontal 7-max via prefix/suffix ----
        #pragma unroll
        for (int r = 0; r < 7; r++) {
            // v0..v9 = lq.y lq.z lq.w oq.x oq.y oq.z oq.w rq.x rq.y rq.z
            float S3 = oq[r].x;
            float S2 = fmaxf(lq[r].w, S3);
            float S1 = fmaxf(lq[r].z, S2);
            float S0 = fmaxf(lq[r].y, S1);
            float P4 = oq[r].y;
            float P5 = fmaxf(P4, oq[r].z);
            float P6 = fmaxf(P5, oq[r].w);
            float P7 = fmaxf(P6, rq[r].x);
            float P8 = fmaxf(P7, rq[r].y);
            float P9 = fmaxf(P8, rq[r].z);
            h[rb + r] = make_float4(fmaxf(S0, P6), fmaxf(S1, P7),
                                    fmaxf(S2, P8), fmaxf(S3, P9));
            const int rr = rb + r;
            if (rr >= 3 && rr < 3 + BAND) c[rr - 3] = oq[r];
        }
    }
    __syncthreads();   // lc_lo/lc_hi init visible before emits

    // ---- Phase B: vertical window + peak emit (static indices) ----
    #pragma unroll
    for (int ro = 0; ro < BAND; ro++) {
        float4 wm = fmax4(fmax4(fmax4(h[ro], h[ro + 1]),
                                fmax4(h[ro + 2], h[ro + 3])),
                          fmax4(fmax4(h[ro + 4], h[ro + 5]), h[ro + 6]));
        float4 ctr = c[ro];
        const int rg = R0 + ro;
        bool p0 = (ctr.x > NMS_THRESH) && (ctr.x == wm.x);
        bool p1 = (ctr.y > NMS_THRESH) && (ctr.y == wm.y);
        bool p2 = (ctr.z > NMS_THRESH) && (ctr.z == wm.z);
        bool p3 = (ctr.w > NMS_THRESH) && (ctr.w == wm.w);
        int cnt = (int)p0 + (int)p1 + (int)p2 + (int)p3;
        if (cnt) {                                // rare per thread-row
            int s = atomicAdd(&lc_lo, cnt);
            unsigned ib = ((unsigned)rg << 10) | ((unsigned)t << 2);
            float cv[4] = {ctr.x, ctr.y, ctr.z, ctr.w};
            bool  pp[4] = {p0, p1, p2, p3};
            #pragma unroll
            for (int j = 0; j < 4; j++) {
                if (pp[j]) {
                    ull key = ((ull)__float_as_uint(cv[j]) << 32) |
                              (ull)(0xFFFFFFFFu - (ib + j));
                    if (s < LBL) lb_lo[s] = key;
                    s++;
                    if (cv[j] > HI_THRESH) {      // ~1/20 of peaks
                        int q = atomicAdd(&lc_hi, 1);
                        if (q < CAPH) lb_hi[q] = key;
                    }
                }
            }
        }
    }

    // ---- flush: coalesced stores to this block's private bucket ----
    __syncthreads();
    const int bkt = img * NBANDS + band;
    const int nl_raw = lc_lo, nh_raw = lc_hi;
    const int nl = min(nl_raw, min(LBL, capl));
    const int nh = min(nh_raw, CAPH);
    ull* glo = cand_lo + (size_t)bkt * capl;
    for (int i = t; i < nl; i += 256) glo[i] = lb_lo[i];
    ull* ghi = cand_hi + (size_t)bkt * CAPH;
    if (t < nh) ghi[t] = lb_hi[t];
    if (t == 0) {
        cntl[bkt] = nl;
        cnth[bkt] = (nh_raw > CAPH) ? -1 : nh_raw;   // -1: force exact lo path
    }
}

// ---------------- Phase 2: per-image exact top-200 ----------------
// hi buckets (> 0.999) total ~1000 keys; if nh_total >= 200 and no bucket
// overflowed, top-200 is provably inside hi (every non-hi value <= 0.999 <
// any hi value). Staged to LDS, radix-select over value bits, exact
// tie-break via full-key bitonic sort. Fallback: bucketed scan of lo lists
// (= ALL peaks).
__global__ __launch_bounds__(256) void topk_kernel(
    const ull* __restrict__ cand_hi,
    const ull* __restrict__ cand_lo,
    const int* __restrict__ cntl,
    const int* __restrict__ cnth,
    float* __restrict__ out,
    int capl)
{
    const int img = blockIdx.x;
    const int t = threadIdx.x;
    const int wv = t >> 6;
    __shared__ ull stage[NBANDS * CAPH];   // 32 KB: all hi keys fit
    __shared__ unsigned hist[4][256];      // wave-private histograms
    __shared__ unsigned sfx[256];
    __shared__ ull sel[256];
    __shared__ int s_ch[NBANDS], s_cl[NBANDS], s_oh[NBANDS + 1];
    __shared__ int s_ok;
    __shared__ int scnt;
    __shared__ unsigned s_pref;
    __shared__ int s_k;

    if (t == 0) s_ok = 1;
    __syncthreads();
    if (t < NBANDS) {
        int raw = cnth[img * NBANDS + t];
        s_ch[t] = max(raw, 0);
        s_cl[t] = cntl[img * NBANDS + t];
        if (raw < 0) s_ok = 0;       // benign race: all writers store 0
    }
    __syncthreads();
    if (t == 0) {
        int a = 0;
        for (int b = 0; b < NBANDS; b++) { s_oh[b] = a; a += s_ch[b]; }
        s_oh[NBANDS] = a;
    }
    __syncthreads();
    const int nh = s_oh[NBANDS];
    const bool use_hi = (nh >= TOPK) && (s_ok != 0);

    if (use_hi) {
        int b = t >> 1, i0 = t & 1;              // 2 threads per band
        int nb = s_ch[b], ob = s_oh[b];
        const ull* p = cand_hi + (size_t)(img * NBANDS + b) * CAPH;
        for (int i = i0; i < nb; i += 2) stage[ob + i] = p[i];
    }
    __syncthreads();

    int n_tot = nh;
    if (!use_hi) {
        n_tot = 0;
        for (int b = 0; b < NBANDS; b++) n_tot += s_cl[b];
    }

    unsigned T = 0;   // value-bits threshold (200th-largest value)
    if (n_tot > TOPK) {
        unsigned prefix = 0, maskhi = 0;
        int kk = TOPK;
        for (int byte = 3; byte >= 0; byte--) {
            #pragma unroll
            for (int w = 0; w < 4; w++) hist[w][t] = 0;
            __syncthreads();
            const int shift = byte * 8;
            if (use_hi) {
                for (int i = t; i < nh; i += 256) {
                    unsigned vb = (unsigned)(stage[i] >> 32);
                    if ((vb & maskhi) == prefix)
                        atomicAdd(&hist[wv][(vb >> shift) & 0xFFu], 1u);
                }
            } else {
                for (int b = 0; b < NBANDS; b++) {
                    int nb = s_cl[b];
                    const ull* p = cand_lo + (size_t)(img * NBANDS + b) * capl;
                    for (int i = t; i < nb; i += 256) {
                        unsigned vb = (unsigned)(p[i] >> 32);
                        if ((vb & maskhi) == prefix)
                            atomicAdd(&hist[wv][(vb >> shift) & 0xFFu], 1u);
                    }
                }
            }
            __syncthreads();
            sfx[t] = hist[0][t] + hist[1][t] + hist[2][t] + hist[3][t];
            __syncthreads();
            for (int off = 1; off < 256; off <<= 1) {
                unsigned u = (t + off < 256) ? sfx[t + off] : 0u;
                __syncthreads();
                sfx[t] += u;
                __syncthreads();
            }
            unsigned nxt = (t == 255) ? 0u : sfx[t + 1];
            if (sfx[t] >= (unsigned)kk && nxt < (unsigned)kk) {
                s_pref = prefix | ((unsigned)t << shift);
                s_k = kk - (int)nxt;
            }
            __syncthreads();
            prefix = s_pref;
            kk = s_k;
            maskhi |= (0xFFu << shift);
            __syncthreads();
        }
        T = prefix;
    }

    if (t == 0) scnt = 0;
    __syncthreads();
    if (use_hi) {
        for (int i = t; i < nh; i += 256) {
            ull k = stage[i];
            if ((unsigned)(k >> 32) >= T) {
                int s = atomicAdd(&scnt, 1);
                if (s < 256) sel[s] = k;
            }
        }
    } else {
        for (int b = 0; b < NBANDS; b++) {
            int nb = s_cl[b];
            const ull* p = cand_lo + (size_t)(img * NBANDS + b) * capl;
            for (int i = t; i < nb; i += 256) {
                ull k = p[i];
                if ((unsigned)(k >> 32) >= T) {
                    int s = atomicAdd(&scnt, 1);
                    if (s < 256) sel[s] = k;
                }
            }
        }
    }
    __syncthreads();
    const int m = min(scnt, 256);
    if (t >= m) sel[t] = 0ull;
    __syncthreads();

    // bitonic sort 256 keys, descending
    for (int k2 = 2; k2 <= 256; k2 <<= 1) {
        for (int j = k2 >> 1; j > 0; j >>= 1) {
            int ixj = t ^ j;
            if (ixj > t) {
                ull a = sel[t], b = sel[ixj];
                bool descBlock = ((t & k2) == 0);
                bool sw = descBlock ? (a < b) : (a > b);
                if (sw) { sel[t] = b; sel[ixj] = a; }
            }
            __syncthreads();
        }
    }

    // write: coords [NB,TOPK,2] then probs [NB,TOPK], all fp32
    const int meff = min(m, TOPK);
    if (t < TOPK) {
        float prob = 0.0f;
        unsigned row = 0, col = 0;
        if (t < meff) {
            ull key = sel[t];
            prob = __uint_as_float((unsigned)(key >> 32));
            unsigned idx = 0xFFFFFFFFu - (unsigned)(key & 0xFFFFFFFFull);
            row = idx >> 10;
            col = idx & (W - 1);
        }
        size_t cbase = (size_t)img * TOPK * 2 + (size_t)t * 2;
        out[cbase + 0] = (float)row;
        out[cbase + 1] = (float)col;
        out[(size_t)NB * TOPK * 2 + (size_t)img * TOPK + t] = prob;
    }
}

extern "C" void kernel_launch(void* const* d_in, const int* in_sizes, int n_in,
                              void* d_out, int out_size, void* d_ws, size_t ws_size,
                              hipStream_t stream) {
    const float* center_map = (const float*)d_in[0];
    float* out = (float*)d_out;

    // workspace layout (all counts plain-stored by peak_kernel; no memset):
    //   [0, 16K)      : cntl[4096]
    //   [16K, 32K)    : cnth[4096]
    //   [32K, +1M)    : cand_hi[4096][CAPH]
    //   rest          : cand_lo[4096][capl]
    const int nbkt = NB * NBANDS;   // 4096
    int* cntl = (int*)d_ws;
    int* cnth = (int*)((char*)d_ws + 16384);
    ull* cand_hi = (ull*)((char*)d_ws + 32768);
    size_t hi_bytes = (size_t)nbkt * CAPH * sizeof(ull);   // 1 MB
    ull* cand_lo = (ull*)((char*)d_ws + 32768 + hi_bytes);
    size_t avail = (ws_size > 32768 + hi_bytes) ? (ws_size - 32768 - hi_bytes) : 0;
    int capl = (int)(avail / (nbkt * sizeof(ull)));
    if (capl > LBL) capl = LBL;
    if (capl < 1) capl = 1;

    dim3 gridA(NBANDS, NB);   // 128 x 32 = 4096 blocks
    peak_kernel<<<gridA, 256, 0, stream>>>(center_map, cand_hi, cand_lo,
                                           cntl, cnth, capl);

    topk_kernel<<<NB, 256, 0, stream>>>(cand_hi, cand_lo, cntl, cnth, out, capl);
}